// Round 3
// baseline (7877.947 us; speedup 1.0000x reference)
//
#include <hip/hip_runtime.h>

#define M_NODES 20000
#define K_FEATS 3703
#define PADK 3712          // 116*32
#define NH 50
#define NC 6
#define N_EDGES_C 640000
#define BM 256             // rows per block
#define BK 32              // k per LDS tile

// ================= pad W1 -> Bp[3712][64], zero-filled =================
__global__ void k_padB(const float* __restrict__ W1, float* __restrict__ Bp) {
  int idx = blockIdx.x * 256 + threadIdx.x;
  if (idx >= PADK * 64) return;
  int k = idx >> 6, c = idx & 63;
  Bp[idx] = (k < K_FEATS && c < NH) ? W1[k * NH + c] : 0.f;
}

// ================= GEMM1: part[s] = A[:, ks:ke] @ W1[ks:ke, :] =================
// 256 threads = 32 rslots x 8 cg; thread tile 8 rows (rslot+32i) x 8 cols (cg*8..+7).
// A: double-buffered 2x32KB LDS, XOR-swizzled (kk ^ (r&7)<<2) -> conflict-free b128.
// B: direct from L2-resident Bp via rolling 4-deep float4 prefetch (bv).
// Staging: T14 issue-early (loads at iter top) / write-late (ds_write after compute).
__global__ __launch_bounds__(256) void k_gemm1(const float* __restrict__ A,
                                               const float* __restrict__ Bp,
                                               float* __restrict__ part, int KS) {
  __shared__ float lA[2][BM * BK];     // 65536 B
  const int tid = threadIdx.x;
  const int row0 = blockIdx.x * BM;
  const int s = blockIdx.y;
  const int ks = s * KS;
  const int ke = (ks + KS < PADK) ? ks + KS : PADK;
  const int nsteps = (ke - ks) >> 5;
  const int rslot = tid >> 3;          // 0..31
  const int cg = tid & 7;              // 0..7
  const int swz = (rslot & 7) << 2;    // float-index XOR within a 32-float row

  float acc[8][8];
  #pragma unroll
  for (int i = 0; i < 8; ++i)
    #pragma unroll
    for (int j = 0; j < 8; ++j) acc[i][j] = 0.f;

  float ra[32];

  // ---- prologue: stage tile 0, preload B pipeline ----
  #pragma unroll
  for (int u = 0; u < 32; ++u) {
    int f = tid + u * 256;
    int r = f >> 5, kk = f & 31;
    int gr = row0 + r, gk = ks + kk;
    ra[u] = (gr < M_NODES && gk < K_FEATS) ? A[(size_t)gr * K_FEATS + gk] : 0.f;
  }
  #pragma unroll
  for (int u = 0; u < 32; ++u) {
    int f = tid + u * 256;
    int r = f >> 5, kk = f & 31;
    lA[0][r * 32 + (kk ^ ((r & 7) << 2))] = ra[u];
  }
  float4 bv[4][2];
  #pragma unroll
  for (int p = 0; p < 4; ++p) {
    const float4* Br = (const float4*)(Bp + (size_t)(ks + p) * 64 + cg * 8);
    bv[p][0] = Br[0];
    bv[p][1] = Br[1];
  }
  __syncthreads();

  for (int t = 0; t < nsteps; ++t) {
    const int k0 = ks + (t << 5);
    const bool more = (t + 1 < nsteps);
    // issue-early: next A tile global loads (HBM latency hides under compute)
    if (more) {
      const int k1 = k0 + 32;
      #pragma unroll
      for (int u = 0; u < 32; ++u) {
        int f = tid + u * 256;
        int r = f >> 5, kk = f & 31;
        int gr = row0 + r, gk = k1 + kk;
        ra[u] = (gr < M_NODES && gk < K_FEATS) ? A[(size_t)gr * K_FEATS + gk] : 0.f;
      }
    }
    const float* la = lA[t & 1];
    #pragma unroll
    for (int kk4 = 0; kk4 < 8; ++kk4) {
      float4 av[8];
      #pragma unroll
      for (int i = 0; i < 8; ++i)
        av[i] = *(const float4*)&la[(rslot + 32 * i) * 32 + ((kk4 * 4) ^ swz)];
      #pragma unroll
      for (int kkin = 0; kkin < 4; ++kkin) {
        float4 b0 = bv[kkin][0], b1 = bv[kkin][1];
        // rolling B prefetch, 4 kk ahead (crosses tile boundary; clamp in-bounds)
        int kpre = k0 + kk4 * 4 + kkin + 4;
        kpre = (kpre < PADK - 1) ? kpre : PADK - 1;
        const float4* Br = (const float4*)(Bp + (size_t)kpre * 64 + cg * 8);
        bv[kkin][0] = Br[0];
        bv[kkin][1] = Br[1];
        #pragma unroll
        for (int i = 0; i < 8; ++i) {
          float aa = ((const float*)&av[i])[kkin];
          acc[i][0] = fmaf(aa, b0.x, acc[i][0]);
          acc[i][1] = fmaf(aa, b0.y, acc[i][1]);
          acc[i][2] = fmaf(aa, b0.z, acc[i][2]);
          acc[i][3] = fmaf(aa, b0.w, acc[i][3]);
          acc[i][4] = fmaf(aa, b1.x, acc[i][4]);
          acc[i][5] = fmaf(aa, b1.y, acc[i][5]);
          acc[i][6] = fmaf(aa, b1.z, acc[i][6]);
          acc[i][7] = fmaf(aa, b1.w, acc[i][7]);
        }
      }
    }
    // write-late: commit next tile to the other LDS buffer, one barrier per k-step
    if (more) {
      float* ln = lA[(t + 1) & 1];
      #pragma unroll
      for (int u = 0; u < 32; ++u) {
        int f = tid + u * 256;
        int r = f >> 5, kk = f & 31;
        ln[r * 32 + (kk ^ ((r & 7) << 2))] = ra[u];
      }
      __syncthreads();
    }
  }

  float* p = part + (size_t)s * 1000000;
  #pragma unroll
  for (int i = 0; i < 8; ++i) {
    int gr = row0 + rslot + 32 * i;
    if (gr < M_NODES) {
      #pragma unroll
      for (int j = 0; j < 8; ++j) {
        int c = cg * 8 + j;
        if (c < NH) p[gr * NH + c] = acc[i][j];
      }
    }
  }
}

// ================= epilogue: x1 = relu(sum_s part[s] + b1) =================
__global__ void k_epi(const float* __restrict__ part, const float* __restrict__ b1,
                      float* __restrict__ x1, int S) {
  int i = blockIdx.x * 256 + threadIdx.x;
  if (i >= M_NODES * NH) return;
  float v = b1[i % NH];
  for (int s = 0; s < S; ++s) v += part[(size_t)s * 1000000 + i];
  x1[i] = fmaxf(v, 0.f);
}

// ================= fused MLP layers 2..4 =================
__global__ __launch_bounds__(256) void k_mlp(const float* __restrict__ x1,
    const float* __restrict__ W2, const float* __restrict__ b2,
    const float* __restrict__ W3, const float* __restrict__ b3,
    const float* __restrict__ W4, const float* __restrict__ b4,
    float* __restrict__ z) {
  __shared__ float lX[32 * 51];
  __shared__ float lW2[50 * 52];
  __shared__ float lW3[50 * 52];
  __shared__ float lW4[50 * 8];
  const int tid = threadIdx.x;
  const int row0 = blockIdx.x * 32;
  for (int idx = tid; idx < 2500; idx += 256) {
    int k = idx / 50, n = idx % 50;
    lW2[k * 52 + n] = W2[idx];
    lW3[k * 52 + n] = W3[idx];
  }
  for (int idx = tid; idx < 300; idx += 256) {
    int k = idx / 6, n = idx % 6;
    lW4[k * 8 + n] = W4[idx];
  }
  for (int idx = tid; idx < 1600; idx += 256) {
    int r = idx / 50, k = idx % 50;
    int gr = row0 + r;
    lX[r * 51 + k] = (gr < M_NODES) ? x1[gr * 50 + k] : 0.f;
  }
  __syncthreads();
  const int r = tid >> 3, cg = tid & 7;
  float x[50];
  #pragma unroll
  for (int k = 0; k < 50; ++k) x[k] = lX[r * 51 + k];

  for (int layer = 0; layer < 2; ++layer) {
    const float* lW = (layer == 0) ? lW2 : lW3;
    const float* bg = (layer == 0) ? b2 : b3;
    float acc[7];
    #pragma unroll
    for (int j = 0; j < 7; ++j) {
      int n = cg + 8 * j;
      acc[j] = (n < 50) ? bg[n] : 0.f;
    }
    #pragma unroll
    for (int k = 0; k < 50; ++k) {
      float xk = x[k];
      #pragma unroll
      for (int j = 0; j < 7; ++j) {
        int n = cg + 8 * j;
        if (n < 50) acc[j] = fmaf(xk, lW[k * 52 + n], acc[j]);
      }
    }
    __syncthreads();
    #pragma unroll
    for (int j = 0; j < 7; ++j) {
      int n = cg + 8 * j;
      if (n < 50) lX[r * 51 + n] = fmaxf(acc[j], 0.f);
    }
    __syncthreads();
    #pragma unroll
    for (int k = 0; k < 50; ++k) x[k] = lX[r * 51 + k];
  }
  if (cg < 6) {
    float accz = b4[cg];
    #pragma unroll
    for (int k = 0; k < 50; ++k) accz = fmaf(x[k], lW4[k * 8 + cg], accz);
    int gr = row0 + r;
    if (gr < M_NODES) z[gr * 6 + cg] = accz;
  }
}

// ================= CSR incidence build =================
__global__ void k_count(const int* __restrict__ sx, const int* __restrict__ sy,
                        int* __restrict__ cnt) {
  int e = blockIdx.x * 256 + threadIdx.x;
  if (e >= N_EDGES_C) return;
  atomicAdd(&cnt[sx[e]], 1);
  atomicAdd(&cnt[sy[e]], 1);
}

__global__ __launch_bounds__(1024) void k_scan(const int* __restrict__ cnt,
                                               int* __restrict__ off,
                                               int* __restrict__ cur) {
  __shared__ int sums[1024];
  int t = threadIdx.x;
  int base = t * 20;
  int local[20];
  int s = 0;
  #pragma unroll
  for (int j = 0; j < 20; ++j) {
    int idx = base + j;
    int v = (idx < M_NODES) ? cnt[idx] : 0;
    local[j] = s;
    s += v;
  }
  sums[t] = s;
  __syncthreads();
  for (int d = 1; d < 1024; d <<= 1) {
    int v = (t >= d) ? sums[t - d] : 0;
    __syncthreads();
    sums[t] += v;
    __syncthreads();
  }
  int excl = sums[t] - s;
  #pragma unroll
  for (int j = 0; j < 20; ++j) {
    int idx = base + j;
    if (idx < M_NODES) {
      int o = excl + local[j];
      off[idx] = o;
      cur[idx] = o;
    }
  }
  if (t == 1023) off[M_NODES] = sums[1023];
}

__global__ void k_scatter(const int* __restrict__ sx, const int* __restrict__ sy,
                          int* __restrict__ cur, int* __restrict__ entries) {
  int e = blockIdx.x * 256 + threadIdx.x;
  if (e >= N_EDGES_C) return;
  int p = atomicAdd(&cur[sx[e]], 1);
  entries[p] = (e << 1);
  int q = atomicAdd(&cur[sy[e]], 1);
  entries[q] = (e << 1) | 1;
}

// ================= KENN gather layer: thread = (node, eighth), all 6 classes =================
__global__ __launch_bounds__(256) void k_gather(const float* __restrict__ z,
    const int* __restrict__ off, const int* __restrict__ entries,
    const int* __restrict__ sx, const int* __restrict__ sy,
    const float* __restrict__ rel, const float* __restrict__ cw,
    float* __restrict__ partial) {
  int t = blockIdx.x * 256 + threadIdx.x;
  if (t >= M_NODES * 8) return;
  int s = t & 7;
  int n = t >> 3;
  int o0 = off[n];
  int deg = off[n + 1] - o0;
  int lo = o0 + ((deg * s) >> 3);
  int hi = o0 + ((deg * (s + 1)) >> 3);

  const float2* zr = (const float2*)(z + n * 6);
  float2 a0 = zr[0], a1 = zr[1], a2 = zr[2];
  float znv[6] = {a0.x, a0.y, a1.x, a1.y, a2.x, a2.y};
  float w[6];
  #pragma unroll
  for (int c = 0; c < 6; ++c) w[c] = cw[c];
  float dz[6] = {0.f, 0.f, 0.f, 0.f, 0.f, 0.f};

  for (int i = lo; i < hi; ++i) {
    int ent = entries[i];
    int e = ent >> 1;
    int side = ent & 1;
    int partner = side ? sx[e] : sy[e];
    float r = rel[e];
    const float2* zp2 = (const float2*)(z + partner * 6);
    float2 p0 = zp2[0], p1 = zp2[1], p2 = zp2[2];
    float zpv[6] = {p0.x, p0.y, p1.x, p1.y, p2.x, p2.y};
    float v2 = -r;
    #pragma unroll
    for (int c = 0; c < 6; ++c) {
      float zx = side ? zpv[c] : znv[c];
      float zy = side ? znv[c] : zpv[c];
      float v0 = -zx, v1 = zy;
      float m = fmaxf(fmaxf(v0, v1), v2);
      float e0 = __expf(v0 - m);
      float e1 = __expf(v1 - m);
      float e2 = __expf(v2 - m);
      float inv = w[c] / (e0 + e1 + e2);
      dz[c] += (side ? e1 : -e0) * inv;
    }
  }
  float* pp = partial + (size_t)s * 120000 + n * 6;
  #pragma unroll
  for (int c = 0; c < 6; ++c) pp[c] = dz[c];
}

__global__ void k_combine(const float* __restrict__ zc, const float* __restrict__ partial,
                          float* __restrict__ zn) {
  int i = blockIdx.x * 256 + threadIdx.x;
  if (i >= M_NODES * NC) return;
  float v = zc[i];
  #pragma unroll
  for (int s = 0; s < 8; ++s) v += partial[(size_t)s * 120000 + i];
  zn[i] = v;
}

// ================= final row softmax =================
__global__ void k_softmax(const float* __restrict__ z, float* __restrict__ out) {
  int i = blockIdx.x * 256 + threadIdx.x;
  if (i >= M_NODES) return;
  const float2* z2 = (const float2*)(z + i * 6);
  float2 p0 = z2[0], p1 = z2[1], p2 = z2[2];
  float v[6] = {p0.x, p0.y, p1.x, p1.y, p2.x, p2.y};
  float m = v[0];
  #pragma unroll
  for (int c = 1; c < 6; ++c) m = fmaxf(m, v[c]);
  float sum = 0.f, ev[6];
  #pragma unroll
  for (int c = 0; c < 6; ++c) { ev[c] = __expf(v[c] - m); sum += ev[c]; }
  float inv = 1.f / sum;
  float2* o2 = (float2*)(out + i * 6);
  o2[0] = make_float2(ev[0] * inv, ev[1] * inv);
  o2[1] = make_float2(ev[2] * inv, ev[3] * inv);
  o2[2] = make_float2(ev[4] * inv, ev[5] * inv);
}

extern "C" void kernel_launch(void* const* d_in, const int* in_sizes, int n_in,
                              void* d_out, int out_size, void* d_ws, size_t ws_size,
                              hipStream_t stream) {
  const float* A   = (const float*)d_in[0];
  const float* rel = (const float*)d_in[1];
  const int*   sx  = (const int*)d_in[2];
  const int*   sy  = (const int*)d_in[3];
  const float* W1  = (const float*)d_in[4];
  const float* b1  = (const float*)d_in[5];
  const float* W2  = (const float*)d_in[6];
  const float* b2  = (const float*)d_in[7];
  const float* W3  = (const float*)d_in[8];
  const float* b3  = (const float*)d_in[9];
  const float* W4  = (const float*)d_in[10];
  const float* b4  = (const float*)d_in[11];
  const float* cw  = (const float*)d_in[12];

  // split-K: 79 x S blocks; S=13 gives 1027 blocks ~= 2 full residency waves (512)
  size_t wf = ws_size / 4;
  int S, KS;
  if (wf >= 14600000)      { S = 13; KS = 288; }
  else if (wf >= 7600000)  { S = 6;  KS = 640; }
  else                     { S = 4;  KS = 928; }

  float* base = (float*)d_ws;
  float* part = base;                        // S * 1e6 floats (dead after k_epi)
  float* x1   = base + (size_t)S * 1000000;  // 1e6 (dead after k_mlp)
  float* zA   = x1 + 1000000;                // 120000
  float* zB   = zA + 120000;                 // 120000
  float* Bp   = zB + 120000;                 // 237568 (live through k_gemm1)

  // CSR arrays alias the (dead) part region; needs 2.34M floats <= S*1e6 (S>=4)
  int*   cnt     = (int*)base;               // 20001
  int*   off     = (int*)base + 24576;       // 20001
  int*   cur     = (int*)base + 49152;       // 20001
  int*   entries = (int*)base + 73728;       // 1,280,000 -> ends 1,353,728
  float* partial = base + 1376256;           // 8 * 120,000 -> ends 2,336,256

  k_padB<<<(PADK * 64 + 255) / 256, 256, 0, stream>>>(W1, Bp);
  k_gemm1<<<dim3((M_NODES + BM - 1) / BM, S), 256, 0, stream>>>(A, Bp, part, KS);
  k_epi<<<(M_NODES * NH + 255) / 256, 256, 0, stream>>>(part, b1, x1, S);
  k_mlp<<<(M_NODES + 31) / 32, 256, 0, stream>>>(x1, W2, b2, W3, b3, W4, b4, zA);

  hipMemsetAsync(cnt, 0, (M_NODES + 1) * sizeof(int), stream);
  k_count<<<(N_EDGES_C + 255) / 256, 256, 0, stream>>>(sx, sy, cnt);
  k_scan<<<1, 1024, 0, stream>>>(cnt, off, cur);
  k_scatter<<<(N_EDGES_C + 255) / 256, 256, 0, stream>>>(sx, sy, cur, entries);

  float* zc = zA;
  float* zn = zB;
  for (int l = 0; l < 3; ++l) {
    k_gather<<<(M_NODES * 8 + 255) / 256, 256, 0, stream>>>(
        zc, off, entries, sx, sy, rel, cw + 6 * l, partial);
    k_combine<<<(M_NODES * NC + 255) / 256, 256, 0, stream>>>(zc, partial, zn);
    float* t = zc; zc = zn; zn = t;
  }
  k_softmax<<<(M_NODES + 255) / 256, 256, 0, stream>>>(zc, (float*)d_out);
}

// Round 4
// 722.800 us; speedup vs baseline: 10.8992x; 10.8992x over previous
//
#include <hip/hip_runtime.h>

#define M_NODES 20000
#define K_FEATS 3703
#define PADK 3712          // 116*32
#define NH 50
#define NC 6
#define N_EDGES_C 640000

// ================= pad W1 -> Bp[3712][64], zero-filled =================
__global__ void k_padB(const float* __restrict__ W1, float* __restrict__ Bp) {
  int idx = blockIdx.x * 256 + threadIdx.x;
  if (idx >= PADK * 64) return;
  int k = idx >> 6, c = idx & 63;
  Bp[idx] = (k < K_FEATS && c < NH) ? W1[k * NH + c] : 0.f;
}

// ================= GEMM1: part[s] = A[:, ks:ke] @ W1[ks:ke, :] =================
// Proven round-2 kernel (88 VGPR, 18KB LDS): 128-row tile, thread = 4 rows x 8 cols,
// A staged in LDS (36-pad), B direct from L2-resident Bp via 4-deep float4 prefetch.
// Round-4 change is ONLY the grid: split-K S=13 -> 2041 blocks (~8/CU) for latency hiding.
__global__ __launch_bounds__(256) void k_gemm1(const float* __restrict__ A,
                                               const float* __restrict__ Bp,
                                               float* __restrict__ part, int KS) {
  __shared__ float lA[128 * 36];
  const int tid = threadIdx.x;
  const int row0 = blockIdx.x * 128;
  const int s = blockIdx.y;
  const int ks = s * KS;
  const int ke = (ks + KS < PADK) ? ks + KS : PADK;     // multiple of 32
  const int keA = (ke < K_FEATS) ? ke : K_FEATS;
  const int rslot = tid >> 3;
  const int cg = tid & 7;

  float4 acc[4][2];
  #pragma unroll
  for (int i = 0; i < 4; ++i) {
    acc[i][0] = make_float4(0.f, 0.f, 0.f, 0.f);
    acc[i][1] = make_float4(0.f, 0.f, 0.f, 0.f);
  }

  for (int k0 = ks; k0 < ke; k0 += 32) {
    // ---- stage A tile 128x32 (coalesced: 32 lanes walk k within a row) ----
    #pragma unroll
    for (int u = 0; u < 16; ++u) {
      int idx = tid + u * 256;            // exactly 4096
      int r = idx >> 5, kk = idx & 31;
      int gr = row0 + r, gk = k0 + kk;
      float v = (gr < M_NODES && gk < keA) ? A[(size_t)gr * K_FEATS + gk] : 0.f;
      lA[r * 36 + kk] = v;
    }
    __syncthreads();

    // ---- preload B pipeline: bv[p] holds B[k0+p][cg*8..+7] ----
    float4 bv[4][2];
    #pragma unroll
    for (int p = 0; p < 4; ++p) {
      const float4* Br = (const float4*)(Bp + (size_t)(k0 + p) * 64 + cg * 8);
      bv[p][0] = Br[0];
      bv[p][1] = Br[1];
    }

    #pragma unroll
    for (int kk4 = 0; kk4 < 8; ++kk4) {
      float4 av[4];
      #pragma unroll
      for (int i = 0; i < 4; ++i)
        av[i] = *(const float4*)&lA[(rslot + 32 * i) * 36 + kk4 * 4];
      #pragma unroll
      for (int kkin = 0; kkin < 4; ++kkin) {
        float4 b0 = bv[kkin][0], b1 = bv[kkin][1];
        if (kk4 < 7) {  // prefetch kk+4 (distance = 4 kk)
          const float4* Br =
              (const float4*)(Bp + (size_t)(k0 + kk4 * 4 + kkin + 4) * 64 + cg * 8);
          bv[kkin][0] = Br[0];
          bv[kkin][1] = Br[1];
        }
        #pragma unroll
        for (int i = 0; i < 4; ++i) {
          float a = ((const float*)&av[i])[kkin];
          acc[i][0].x = fmaf(a, b0.x, acc[i][0].x);
          acc[i][0].y = fmaf(a, b0.y, acc[i][0].y);
          acc[i][0].z = fmaf(a, b0.z, acc[i][0].z);
          acc[i][0].w = fmaf(a, b0.w, acc[i][0].w);
          acc[i][1].x = fmaf(a, b1.x, acc[i][1].x);
          acc[i][1].y = fmaf(a, b1.y, acc[i][1].y);
          acc[i][1].z = fmaf(a, b1.z, acc[i][1].z);
          acc[i][1].w = fmaf(a, b1.w, acc[i][1].w);
        }
      }
    }
    __syncthreads();
  }

  float* p = part + (size_t)s * 1000000;
  #pragma unroll
  for (int i = 0; i < 4; ++i) {
    int gr = row0 + rslot + 32 * i;
    if (gr < M_NODES) {
      #pragma unroll
      for (int h = 0; h < 2; ++h) {
        float4 v = acc[i][h];
        int c0 = cg * 8 + h * 4;
        if (c0 + 0 < NH) p[gr * NH + c0 + 0] = v.x;
        if (c0 + 1 < NH) p[gr * NH + c0 + 1] = v.y;
        if (c0 + 2 < NH) p[gr * NH + c0 + 2] = v.z;
        if (c0 + 3 < NH) p[gr * NH + c0 + 3] = v.w;
      }
    }
  }
}

// ================= epilogue: x1 = relu(sum_s part[s] + b1) =================
__global__ void k_epi(const float* __restrict__ part, const float* __restrict__ b1,
                      float* __restrict__ x1, int S) {
  int i = blockIdx.x * 256 + threadIdx.x;
  if (i >= M_NODES * NH) return;
  float v = b1[i % NH];
  for (int s = 0; s < S; ++s) v += part[(size_t)s * 1000000 + i];
  x1[i] = fmaxf(v, 0.f);
}

// ================= fused MLP layers 2..4 =================
__global__ __launch_bounds__(256) void k_mlp(const float* __restrict__ x1,
    const float* __restrict__ W2, const float* __restrict__ b2,
    const float* __restrict__ W3, const float* __restrict__ b3,
    const float* __restrict__ W4, const float* __restrict__ b4,
    float* __restrict__ z) {
  __shared__ float lX[32 * 51];
  __shared__ float lW2[50 * 52];
  __shared__ float lW3[50 * 52];
  __shared__ float lW4[50 * 8];
  const int tid = threadIdx.x;
  const int row0 = blockIdx.x * 32;
  for (int idx = tid; idx < 2500; idx += 256) {
    int k = idx / 50, n = idx % 50;
    lW2[k * 52 + n] = W2[idx];
    lW3[k * 52 + n] = W3[idx];
  }
  for (int idx = tid; idx < 300; idx += 256) {
    int k = idx / 6, n = idx % 6;
    lW4[k * 8 + n] = W4[idx];
  }
  for (int idx = tid; idx < 1600; idx += 256) {
    int r = idx / 50, k = idx % 50;
    int gr = row0 + r;
    lX[r * 51 + k] = (gr < M_NODES) ? x1[gr * 50 + k] : 0.f;
  }
  __syncthreads();
  const int r = tid >> 3, cg = tid & 7;
  float x[50];
  #pragma unroll
  for (int k = 0; k < 50; ++k) x[k] = lX[r * 51 + k];

  for (int layer = 0; layer < 2; ++layer) {
    const float* lW = (layer == 0) ? lW2 : lW3;
    const float* bg = (layer == 0) ? b2 : b3;
    float acc[7];
    #pragma unroll
    for (int j = 0; j < 7; ++j) {
      int n = cg + 8 * j;
      acc[j] = (n < 50) ? bg[n] : 0.f;
    }
    #pragma unroll
    for (int k = 0; k < 50; ++k) {
      float xk = x[k];
      #pragma unroll
      for (int j = 0; j < 7; ++j) {
        int n = cg + 8 * j;
        if (n < 50) acc[j] = fmaf(xk, lW[k * 52 + n], acc[j]);
      }
    }
    __syncthreads();
    #pragma unroll
    for (int j = 0; j < 7; ++j) {
      int n = cg + 8 * j;
      if (n < 50) lX[r * 51 + n] = fmaxf(acc[j], 0.f);
    }
    __syncthreads();
    #pragma unroll
    for (int k = 0; k < 50; ++k) x[k] = lX[r * 51 + k];
  }
  if (cg < 6) {
    float accz = b4[cg];
    #pragma unroll
    for (int k = 0; k < 50; ++k) accz = fmaf(x[k], lW4[k * 8 + cg], accz);
    int gr = row0 + r;
    if (gr < M_NODES) z[gr * 6 + cg] = accz;
  }
}

// ================= CSR incidence build =================
__global__ void k_count(const int* __restrict__ sx, const int* __restrict__ sy,
                        int* __restrict__ cnt) {
  int e = blockIdx.x * 256 + threadIdx.x;
  if (e >= N_EDGES_C) return;
  atomicAdd(&cnt[sx[e]], 1);
  atomicAdd(&cnt[sy[e]], 1);
}

__global__ __launch_bounds__(1024) void k_scan(const int* __restrict__ cnt,
                                               int* __restrict__ off,
                                               int* __restrict__ cur) {
  __shared__ int sums[1024];
  int t = threadIdx.x;
  int base = t * 20;
  int local[20];
  int s = 0;
  #pragma unroll
  for (int j = 0; j < 20; ++j) {
    int idx = base + j;
    int v = (idx < M_NODES) ? cnt[idx] : 0;
    local[j] = s;
    s += v;
  }
  sums[t] = s;
  __syncthreads();
  for (int d = 1; d < 1024; d <<= 1) {
    int v = (t >= d) ? sums[t - d] : 0;
    __syncthreads();
    sums[t] += v;
    __syncthreads();
  }
  int excl = sums[t] - s;
  #pragma unroll
  for (int j = 0; j < 20; ++j) {
    int idx = base + j;
    if (idx < M_NODES) {
      int o = excl + local[j];
      off[idx] = o;
      cur[idx] = o;
    }
  }
  if (t == 1023) off[M_NODES] = sums[1023];
}

__global__ void k_scatter(const int* __restrict__ sx, const int* __restrict__ sy,
                          int* __restrict__ cur, int* __restrict__ entries) {
  int e = blockIdx.x * 256 + threadIdx.x;
  if (e >= N_EDGES_C) return;
  int p = atomicAdd(&cur[sx[e]], 1);
  entries[p] = (e << 1);
  int q = atomicAdd(&cur[sy[e]], 1);
  entries[q] = (e << 1) | 1;
}

// ================= KENN gather layer: thread = (node, eighth), all 6 classes =================
__global__ __launch_bounds__(256) void k_gather(const float* __restrict__ z,
    const int* __restrict__ off, const int* __restrict__ entries,
    const int* __restrict__ sx, const int* __restrict__ sy,
    const float* __restrict__ rel, const float* __restrict__ cw,
    float* __restrict__ partial) {
  int t = blockIdx.x * 256 + threadIdx.x;
  if (t >= M_NODES * 8) return;
  int s = t & 7;
  int n = t >> 3;
  int o0 = off[n];
  int deg = off[n + 1] - o0;
  int lo = o0 + ((deg * s) >> 3);
  int hi = o0 + ((deg * (s + 1)) >> 3);

  const float2* zr = (const float2*)(z + n * 6);
  float2 a0 = zr[0], a1 = zr[1], a2 = zr[2];
  float znv[6] = {a0.x, a0.y, a1.x, a1.y, a2.x, a2.y};
  float w[6];
  #pragma unroll
  for (int c = 0; c < 6; ++c) w[c] = cw[c];
  float dz[6] = {0.f, 0.f, 0.f, 0.f, 0.f, 0.f};

  for (int i = lo; i < hi; ++i) {
    int ent = entries[i];
    int e = ent >> 1;
    int side = ent & 1;
    int partner = side ? sx[e] : sy[e];
    float r = rel[e];
    const float2* zp2 = (const float2*)(z + partner * 6);
    float2 p0 = zp2[0], p1 = zp2[1], p2 = zp2[2];
    float zpv[6] = {p0.x, p0.y, p1.x, p1.y, p2.x, p2.y};
    float v2 = -r;
    #pragma unroll
    for (int c = 0; c < 6; ++c) {
      float zx = side ? zpv[c] : znv[c];
      float zy = side ? znv[c] : zpv[c];
      float v0 = -zx, v1 = zy;
      float m = fmaxf(fmaxf(v0, v1), v2);
      float e0 = __expf(v0 - m);
      float e1 = __expf(v1 - m);
      float e2 = __expf(v2 - m);
      float inv = w[c] / (e0 + e1 + e2);
      dz[c] += (side ? e1 : -e0) * inv;
    }
  }
  float* pp = partial + (size_t)s * 120000 + n * 6;
  #pragma unroll
  for (int c = 0; c < 6; ++c) pp[c] = dz[c];
}

__global__ void k_combine(const float* __restrict__ zc, const float* __restrict__ partial,
                          float* __restrict__ zn) {
  int i = blockIdx.x * 256 + threadIdx.x;
  if (i >= M_NODES * NC) return;
  float v = zc[i];
  #pragma unroll
  for (int s = 0; s < 8; ++s) v += partial[(size_t)s * 120000 + i];
  zn[i] = v;
}

// ================= final row softmax =================
__global__ void k_softmax(const float* __restrict__ z, float* __restrict__ out) {
  int i = blockIdx.x * 256 + threadIdx.x;
  if (i >= M_NODES) return;
  const float2* z2 = (const float2*)(z + i * 6);
  float2 p0 = z2[0], p1 = z2[1], p2 = z2[2];
  float v[6] = {p0.x, p0.y, p1.x, p1.y, p2.x, p2.y};
  float m = v[0];
  #pragma unroll
  for (int c = 1; c < 6; ++c) m = fmaxf(m, v[c]);
  float sum = 0.f, ev[6];
  #pragma unroll
  for (int c = 0; c < 6; ++c) { ev[c] = __expf(v[c] - m); sum += ev[c]; }
  float inv = 1.f / sum;
  float2* o2 = (float2*)(out + i * 6);
  o2[0] = make_float2(ev[0] * inv, ev[1] * inv);
  o2[1] = make_float2(ev[2] * inv, ev[3] * inv);
  o2[2] = make_float2(ev[4] * inv, ev[5] * inv);
}

extern "C" void kernel_launch(void* const* d_in, const int* in_sizes, int n_in,
                              void* d_out, int out_size, void* d_ws, size_t ws_size,
                              hipStream_t stream) {
  const float* A   = (const float*)d_in[0];
  const float* rel = (const float*)d_in[1];
  const int*   sx  = (const int*)d_in[2];
  const int*   sy  = (const int*)d_in[3];
  const float* W1  = (const float*)d_in[4];
  const float* b1  = (const float*)d_in[5];
  const float* W2  = (const float*)d_in[6];
  const float* b2  = (const float*)d_in[7];
  const float* W3  = (const float*)d_in[8];
  const float* b3  = (const float*)d_in[9];
  const float* W4  = (const float*)d_in[10];
  const float* b4  = (const float*)d_in[11];
  const float* cw  = (const float*)d_in[12];

  // split-K: 157 x S blocks; S=13 -> 2041 blocks (~8/CU issued, 4/CU resident)
  size_t wf = ws_size / 4;
  int S, KS;
  if (wf >= 14600000)      { S = 13; KS = 288; }
  else if (wf >= 7600000)  { S = 6;  KS = 640; }
  else                     { S = 4;  KS = 928; }

  float* base = (float*)d_ws;
  float* part = base;                        // S * 1e6 floats (dead after k_epi)
  float* x1   = base + (size_t)S * 1000000;  // 1e6 (dead after k_mlp)
  float* zA   = x1 + 1000000;                // 120000
  float* zB   = zA + 120000;                 // 120000
  float* Bp   = zB + 120000;                 // 237568 (live through k_gemm1)

  // CSR arrays alias the (dead) part region; needs 2.34M floats <= S*1e6 (S>=4)
  int*   cnt     = (int*)base;               // 20001
  int*   off     = (int*)base + 24576;       // 20001
  int*   cur     = (int*)base + 49152;       // 20001
  int*   entries = (int*)base + 73728;       // 1,280,000 -> ends 1,353,728
  float* partial = base + 1376256;           // 8 * 120,000 -> ends 2,336,256

  k_padB<<<(PADK * 64 + 255) / 256, 256, 0, stream>>>(W1, Bp);
  k_gemm1<<<dim3(157, S), 256, 0, stream>>>(A, Bp, part, KS);
  k_epi<<<(M_NODES * NH + 255) / 256, 256, 0, stream>>>(part, b1, x1, S);
  k_mlp<<<(M_NODES + 31) / 32, 256, 0, stream>>>(x1, W2, b2, W3, b3, W4, b4, zA);

  hipMemsetAsync(cnt, 0, (M_NODES + 1) * sizeof(int), stream);
  k_count<<<(N_EDGES_C + 255) / 256, 256, 0, stream>>>(sx, sy, cnt);
  k_scan<<<1, 1024, 0, stream>>>(cnt, off, cur);
  k_scatter<<<(N_EDGES_C + 255) / 256, 256, 0, stream>>>(sx, sy, cur, entries);

  float* zc = zA;
  float* zn = zB;
  for (int l = 0; l < 3; ++l) {
    k_gather<<<(M_NODES * 8 + 255) / 256, 256, 0, stream>>>(
        zc, off, entries, sx, sy, rel, cw + 6 * l, partial);
    k_combine<<<(M_NODES * NC + 255) / 256, 256, 0, stream>>>(zc, partial, zn);
    float* t = zc; zc = zn; zn = t;
  }
  k_softmax<<<(M_NODES + 255) / 256, 256, 0, stream>>>(zc, (float*)d_out);
}

// Round 5
// 357.098 us; speedup vs baseline: 22.0610x; 2.0241x over previous
//
#include <hip/hip_runtime.h>

#define M_NODES 20000
#define K_FEATS 3703
#define PADK 3712          // 116*32
#define NH 50
#define NC 6
#define N_EDGES_C 640000
#define NKB 116            // PADK/32 k-blocks

typedef __attribute__((ext_vector_type(8))) __bf16 bf16x8;
typedef __attribute__((ext_vector_type(4))) float f32x4;

// ============ pack W1 -> MFMA B-fragment layout, bf16 hi/lo ============
// Bpack[kb][t][lane][j] = W1[kb*32 + (lane>>4)*8 + j][t*16 + (lane&15)], zero-padded.
__global__ void k_packB(const float* __restrict__ W1, unsigned short* __restrict__ Bh,
                        unsigned short* __restrict__ Bl) {
  int idx = blockIdx.x * 256 + threadIdx.x;
  if (idx >= NKB * 4 * 64 * 8) return;
  int j = idx & 7;
  int lane = (idx >> 3) & 63;
  int t = (idx >> 9) & 3;
  int kb = idx >> 11;
  int k = kb * 32 + (lane >> 4) * 8 + j;
  int c = t * 16 + (lane & 15);
  float v = (k < K_FEATS && c < NH) ? W1[k * NH + c] : 0.f;
  __bf16 hb = (__bf16)v;
  float hf = (float)hb;
  __bf16 lb = (__bf16)(v - hf);
  Bh[idx] = *(unsigned short*)&hb;
  Bl[idx] = *(unsigned short*)&lb;
}

// ============ GEMM1 via MFMA bf16x3: part[s] = A[:,ks:ke] @ W1[ks:ke,:] ============
// Block = 4 waves x 32 rows = 128 rows, full 64 padded cols. No LDS, no barriers.
// Wave tile: 2 m-tiles x 4 n-tiles of 16x16, K-step 32, 24 MFMA per step.
__global__ __launch_bounds__(256) void k_gemm1(const float* __restrict__ A,
    const unsigned short* __restrict__ Bph, const unsigned short* __restrict__ Bpl,
    float* __restrict__ part, int KS) {
  const int lane = threadIdx.x & 63;
  const int w = threadIdx.x >> 6;
  const int row0 = blockIdx.x * 128 + w * 32;
  const int s = blockIdx.y;
  const int ks = s * KS;
  const int ke = (ks + KS < PADK) ? ks + KS : PADK;
  const int nsteps = (ke - ks) >> 5;         // even by construction (KS=512)
  const int g = lane >> 4;
  const int rl = lane & 15;
  const int r0c = min(row0 + rl, M_NODES - 1);
  const int r1c = min(row0 + 16 + rl, M_NODES - 1);
  const float* a0p = A + (size_t)r0c * K_FEATS + 8 * g;
  const float* a1p = A + (size_t)r1c * K_FEATS + 8 * g;
  const bf16x8* BH = (const bf16x8*)Bph;
  const bf16x8* BL = (const bf16x8*)Bpl;

  f32x4 acc[2][4];
  #pragma unroll
  for (int i = 0; i < 2; ++i)
    #pragma unroll
    for (int t = 0; t < 4; ++t) acc[i][t] = (f32x4){0.f, 0.f, 0.f, 0.f};

  // fast A load: 8 consecutive fp32 per m-tile (dword-aligned dwordx4 is legal)
  #define LOADA(d0, d1, k0) {                                     \
    d0[0] = *(const float4*)(a0p + (k0));                         \
    d0[1] = *(const float4*)(a0p + (k0) + 4);                     \
    d1[0] = *(const float4*)(a1p + (k0));                         \
    d1[1] = *(const float4*)(a1p + (k0) + 4); }
  // guarded tail load (k0+32 > K_FEATS): zero-fill out-of-range k
  #define LOADAG(d0, d1, k0) {                                    \
    _Pragma("unroll") for (int j = 0; j < 8; ++j) {               \
      int gk = (k0) + 8 * g + j;                                  \
      float v0 = (gk < K_FEATS) ? a0p[(k0) + j] : 0.f;            \
      float v1 = (gk < K_FEATS) ? a1p[(k0) + j] : 0.f;            \
      ((float*)d0)[j] = v0; ((float*)d1)[j] = v1; } }

  #define BODY(sa0, sa1, k0) {                                    \
    const int kb4 = ((k0) >> 5) * 4;                              \
    bf16x8 bh0 = BH[(kb4 + 0) * 64 + lane];                       \
    bf16x8 bh1 = BH[(kb4 + 1) * 64 + lane];                       \
    bf16x8 bh2 = BH[(kb4 + 2) * 64 + lane];                       \
    bf16x8 bh3 = BH[(kb4 + 3) * 64 + lane];                       \
    bf16x8 bl0 = BL[(kb4 + 0) * 64 + lane];                       \
    bf16x8 bl1 = BL[(kb4 + 1) * 64 + lane];                       \
    bf16x8 bl2 = BL[(kb4 + 2) * 64 + lane];                       \
    bf16x8 bl3 = BL[(kb4 + 3) * 64 + lane];                       \
    bf16x8 ah0, al0, ah1, al1;                                    \
    _Pragma("unroll") for (int j = 0; j < 8; ++j) {               \
      float xv = ((const float*)sa0)[j];                          \
      __bf16 hb = (__bf16)xv; float hf = (float)hb;               \
      ah0[j] = hb; al0[j] = (__bf16)(xv - hf);                    \
      float yv = ((const float*)sa1)[j];                          \
      __bf16 hb2 = (__bf16)yv; float hf2 = (float)hb2;            \
      ah1[j] = hb2; al1[j] = (__bf16)(yv - hf2);                  \
    }                                                             \
    acc[0][0] = __builtin_amdgcn_mfma_f32_16x16x32_bf16(ah0, bh0, acc[0][0], 0, 0, 0); \
    acc[0][1] = __builtin_amdgcn_mfma_f32_16x16x32_bf16(ah0, bh1, acc[0][1], 0, 0, 0); \
    acc[0][2] = __builtin_amdgcn_mfma_f32_16x16x32_bf16(ah0, bh2, acc[0][2], 0, 0, 0); \
    acc[0][3] = __builtin_amdgcn_mfma_f32_16x16x32_bf16(ah0, bh3, acc[0][3], 0, 0, 0); \
    acc[1][0] = __builtin_amdgcn_mfma_f32_16x16x32_bf16(ah1, bh0, acc[1][0], 0, 0, 0); \
    acc[1][1] = __builtin_amdgcn_mfma_f32_16x16x32_bf16(ah1, bh1, acc[1][1], 0, 0, 0); \
    acc[1][2] = __builtin_amdgcn_mfma_f32_16x16x32_bf16(ah1, bh2, acc[1][2], 0, 0, 0); \
    acc[1][3] = __builtin_amdgcn_mfma_f32_16x16x32_bf16(ah1, bh3, acc[1][3], 0, 0, 0); \
    acc[0][0] = __builtin_amdgcn_mfma_f32_16x16x32_bf16(al0, bh0, acc[0][0], 0, 0, 0); \
    acc[0][1] = __builtin_amdgcn_mfma_f32_16x16x32_bf16(al0, bh1, acc[0][1], 0, 0, 0); \
    acc[0][2] = __builtin_amdgcn_mfma_f32_16x16x32_bf16(al0, bh2, acc[0][2], 0, 0, 0); \
    acc[0][3] = __builtin_amdgcn_mfma_f32_16x16x32_bf16(al0, bh3, acc[0][3], 0, 0, 0); \
    acc[1][0] = __builtin_amdgcn_mfma_f32_16x16x32_bf16(al1, bh0, acc[1][0], 0, 0, 0); \
    acc[1][1] = __builtin_amdgcn_mfma_f32_16x16x32_bf16(al1, bh1, acc[1][1], 0, 0, 0); \
    acc[1][2] = __builtin_amdgcn_mfma_f32_16x16x32_bf16(al1, bh2, acc[1][2], 0, 0, 0); \
    acc[1][3] = __builtin_amdgcn_mfma_f32_16x16x32_bf16(al1, bh3, acc[1][3], 0, 0, 0); \
    acc[0][0] = __builtin_amdgcn_mfma_f32_16x16x32_bf16(ah0, bl0, acc[0][0], 0, 0, 0); \
    acc[0][1] = __builtin_amdgcn_mfma_f32_16x16x32_bf16(ah0, bl1, acc[0][1], 0, 0, 0); \
    acc[0][2] = __builtin_amdgcn_mfma_f32_16x16x32_bf16(ah0, bl2, acc[0][2], 0, 0, 0); \
    acc[0][3] = __builtin_amdgcn_mfma_f32_16x16x32_bf16(ah0, bl3, acc[0][3], 0, 0, 0); \
    acc[1][0] = __builtin_amdgcn_mfma_f32_16x16x32_bf16(ah1, bl0, acc[1][0], 0, 0, 0); \
    acc[1][1] = __builtin_amdgcn_mfma_f32_16x16x32_bf16(ah1, bl1, acc[1][1], 0, 0, 0); \
    acc[1][2] = __builtin_amdgcn_mfma_f32_16x16x32_bf16(ah1, bl2, acc[1][2], 0, 0, 0); \
    acc[1][3] = __builtin_amdgcn_mfma_f32_16x16x32_bf16(ah1, bl3, acc[1][3], 0, 0, 0); }

  float4 xa0[2], xa1[2], ya0[2], ya1[2];
  LOADA(xa0, xa1, ks);                       // step 0 (never a tail step)
  for (int t2 = 0; t2 < nsteps; t2 += 2) {
    const int k0 = ks + (t2 << 5);
    const int k1 = k0 + 32;
    if (k1 + 32 > K_FEATS) { LOADAG(ya0, ya1, k1); } else { LOADA(ya0, ya1, k1); }
    BODY(xa0, xa1, k0);
    if (t2 + 2 < nsteps) {
      const int k2 = k0 + 64;
      if (k2 + 32 > K_FEATS) { LOADAG(xa0, xa1, k2); } else { LOADA(xa0, xa1, k2); }
    }
    BODY(ya0, ya1, k1);
  }
  #undef LOADA
  #undef LOADAG
  #undef BODY

  // C/D layout (m89-verified): col = lane&15, row = (lane>>4)*4 + reg
  float* p = part + (size_t)s * 1000000;
  #pragma unroll
  for (int i = 0; i < 2; ++i) {
    #pragma unroll
    for (int t = 0; t < 4; ++t) {
      int col = t * 16 + rl;
      if (col < NH) {
        int rowb = row0 + i * 16 + g * 4;
        f32x4 v = acc[i][t];
        #pragma unroll
        for (int q = 0; q < 4; ++q) {
          int row = rowb + q;
          if (row < M_NODES) p[row * NH + col] = v[q];
        }
      }
    }
  }
}

// ============ epilogue: x1 = relu(sum_s part[s] + b1) ============
__global__ void k_epi(const float* __restrict__ part, const float* __restrict__ b1,
                      float* __restrict__ x1, int S) {
  int i = blockIdx.x * 256 + threadIdx.x;
  if (i >= M_NODES * NH) return;
  float v = b1[i % NH];
  for (int s = 0; s < S; ++s) v += part[(size_t)s * 1000000 + i];
  x1[i] = fmaxf(v, 0.f);
}

// ============ fused MLP layers 2..4 ============
__global__ __launch_bounds__(256) void k_mlp(const float* __restrict__ x1,
    const float* __restrict__ W2, const float* __restrict__ b2,
    const float* __restrict__ W3, const float* __restrict__ b3,
    const float* __restrict__ W4, const float* __restrict__ b4,
    float* __restrict__ z) {
  __shared__ float lX[32 * 51];
  __shared__ float lW2[50 * 52];
  __shared__ float lW3[50 * 52];
  __shared__ float lW4[50 * 8];
  const int tid = threadIdx.x;
  const int row0 = blockIdx.x * 32;
  for (int idx = tid; idx < 2500; idx += 256) {
    int k = idx / 50, n = idx % 50;
    lW2[k * 52 + n] = W2[idx];
    lW3[k * 52 + n] = W3[idx];
  }
  for (int idx = tid; idx < 300; idx += 256) {
    int k = idx / 6, n = idx % 6;
    lW4[k * 8 + n] = W4[idx];
  }
  for (int idx = tid; idx < 1600; idx += 256) {
    int r = idx / 50, k = idx % 50;
    int gr = row0 + r;
    lX[r * 51 + k] = (gr < M_NODES) ? x1[gr * 50 + k] : 0.f;
  }
  __syncthreads();
  const int r = tid >> 3, cg = tid & 7;
  float x[50];
  #pragma unroll
  for (int k = 0; k < 50; ++k) x[k] = lX[r * 51 + k];

  for (int layer = 0; layer < 2; ++layer) {
    const float* lW = (layer == 0) ? lW2 : lW3;
    const float* bg = (layer == 0) ? b2 : b3;
    float acc[7];
    #pragma unroll
    for (int j = 0; j < 7; ++j) {
      int n = cg + 8 * j;
      acc[j] = (n < 50) ? bg[n] : 0.f;
    }
    #pragma unroll
    for (int k = 0; k < 50; ++k) {
      float xk = x[k];
      #pragma unroll
      for (int j = 0; j < 7; ++j) {
        int n = cg + 8 * j;
        if (n < 50) acc[j] = fmaf(xk, lW[k * 52 + n], acc[j]);
      }
    }
    __syncthreads();
    #pragma unroll
    for (int j = 0; j < 7; ++j) {
      int n = cg + 8 * j;
      if (n < 50) lX[r * 51 + n] = fmaxf(acc[j], 0.f);
    }
    __syncthreads();
    #pragma unroll
    for (int k = 0; k < 50; ++k) x[k] = lX[r * 51 + k];
  }
  if (cg < 6) {
    float accz = b4[cg];
    #pragma unroll
    for (int k = 0; k < 50; ++k) accz = fmaf(x[k], lW4[k * 8 + cg], accz);
    int gr = row0 + r;
    if (gr < M_NODES) z[gr * 6 + cg] = accz;
  }
}

// ============ CSR incidence build ============
__global__ void k_count(const int* __restrict__ sx, const int* __restrict__ sy,
                        int* __restrict__ cnt) {
  int e = blockIdx.x * 256 + threadIdx.x;
  if (e >= N_EDGES_C) return;
  atomicAdd(&cnt[sx[e]], 1);
  atomicAdd(&cnt[sy[e]], 1);
}

__global__ __launch_bounds__(1024) void k_scan(const int* __restrict__ cnt,
                                               int* __restrict__ off,
                                               int* __restrict__ cur) {
  __shared__ int sums[1024];
  int t = threadIdx.x;
  int base = t * 20;
  int local[20];
  int s = 0;
  #pragma unroll
  for (int j = 0; j < 20; ++j) {
    int idx = base + j;
    int v = (idx < M_NODES) ? cnt[idx] : 0;
    local[j] = s;
    s += v;
  }
  sums[t] = s;
  __syncthreads();
  for (int d = 1; d < 1024; d <<= 1) {
    int v = (t >= d) ? sums[t - d] : 0;
    __syncthreads();
    sums[t] += v;
    __syncthreads();
  }
  int excl = sums[t] - s;
  #pragma unroll
  for (int j = 0; j < 20; ++j) {
    int idx = base + j;
    if (idx < M_NODES) {
      int o = excl + local[j];
      off[idx] = o;
      cur[idx] = o;
    }
  }
  if (t == 1023) off[M_NODES] = sums[1023];
}

// packed entry: {partner<<1 | side, rel_bits} — one 8B read per edge-visit in gather
__global__ void k_scatter(const int* __restrict__ sx, const int* __restrict__ sy,
                          const float* __restrict__ rel,
                          int* __restrict__ cur, int2* __restrict__ ent) {
  int e = blockIdx.x * 256 + threadIdx.x;
  if (e >= N_EDGES_C) return;
  int a = sx[e], b = sy[e];
  int rb = __float_as_int(rel[e]);
  int p = atomicAdd(&cur[a], 1);
  ent[p] = make_int2((b << 1), rb);       // node a is x-side (side 0), partner b
  int q = atomicAdd(&cur[b], 1);
  ent[q] = make_int2((a << 1) | 1, rb);   // node b is y-side (side 1), partner a
}

// ============ KENN gather layer: thread = (node, eighth), all 6 classes ============
__global__ __launch_bounds__(256) void k_gather(const float* __restrict__ z,
    const int* __restrict__ off, const int2* __restrict__ ent,
    const float* __restrict__ cw, float* __restrict__ partial) {
  int t = blockIdx.x * 256 + threadIdx.x;
  if (t >= M_NODES * 8) return;
  int s = t & 7;
  int n = t >> 3;
  int o0 = off[n];
  int deg = off[n + 1] - o0;
  int lo = o0 + ((deg * s) >> 3);
  int hi = o0 + ((deg * (s + 1)) >> 3);

  const float2* zr = (const float2*)(z + n * 6);
  float2 a0 = zr[0], a1 = zr[1], a2 = zr[2];
  float znv[6] = {a0.x, a0.y, a1.x, a1.y, a2.x, a2.y};
  float w[6];
  #pragma unroll
  for (int c = 0; c < 6; ++c) w[c] = cw[c];
  float dz[6] = {0.f, 0.f, 0.f, 0.f, 0.f, 0.f};

  for (int i = lo; i < hi; ++i) {
    int2 e2 = ent[i];
    int partner = e2.x >> 1;
    int side = e2.x & 1;
    float r = __int_as_float(e2.y);
    const float2* zp2 = (const float2*)(z + partner * 6);
    float2 p0 = zp2[0], p1 = zp2[1], p2 = zp2[2];
    float zpv[6] = {p0.x, p0.y, p1.x, p1.y, p2.x, p2.y};
    float v2 = -r;
    #pragma unroll
    for (int c = 0; c < 6; ++c) {
      float zx = side ? zpv[c] : znv[c];
      float zy = side ? znv[c] : zpv[c];
      float v0 = -zx, v1 = zy;
      float m = fmaxf(fmaxf(v0, v1), v2);
      float e0 = __expf(v0 - m);
      float e1 = __expf(v1 - m);
      float e2v = __expf(v2 - m);
      float inv = w[c] / (e0 + e1 + e2v);
      dz[c] += (side ? e1 : -e0) * inv;
    }
  }
  float* pp = partial + (size_t)s * 120000 + n * 6;
  #pragma unroll
  for (int c = 0; c < 6; ++c) pp[c] = dz[c];
}

__global__ void k_combine(const float* __restrict__ zc, const float* __restrict__ partial,
                          float* __restrict__ zn) {
  int i = blockIdx.x * 256 + threadIdx.x;
  if (i >= M_NODES * NC) return;
  float v = zc[i];
  #pragma unroll
  for (int s = 0; s < 8; ++s) v += partial[(size_t)s * 120000 + i];
  zn[i] = v;
}

// ============ final row softmax ============
__global__ void k_softmax(const float* __restrict__ z, float* __restrict__ out) {
  int i = blockIdx.x * 256 + threadIdx.x;
  if (i >= M_NODES) return;
  const float2* z2 = (const float2*)(z + i * 6);
  float2 p0 = z2[0], p1 = z2[1], p2 = z2[2];
  float v[6] = {p0.x, p0.y, p1.x, p1.y, p2.x, p2.y};
  float m = v[0];
  #pragma unroll
  for (int c = 1; c < 6; ++c) m = fmaxf(m, v[c]);
  float sum = 0.f, ev[6];
  #pragma unroll
  for (int c = 0; c < 6; ++c) { ev[c] = __expf(v[c] - m); sum += ev[c]; }
  float inv = 1.f / sum;
  float2* o2 = (float2*)(out + i * 6);
  o2[0] = make_float2(ev[0] * inv, ev[1] * inv);
  o2[1] = make_float2(ev[2] * inv, ev[3] * inv);
  o2[2] = make_float2(ev[4] * inv, ev[5] * inv);
}

extern "C" void kernel_launch(void* const* d_in, const int* in_sizes, int n_in,
                              void* d_out, int out_size, void* d_ws, size_t ws_size,
                              hipStream_t stream) {
  const float* A   = (const float*)d_in[0];
  const float* rel = (const float*)d_in[1];
  const int*   sx  = (const int*)d_in[2];
  const int*   sy  = (const int*)d_in[3];
  const float* W1  = (const float*)d_in[4];
  const float* b1  = (const float*)d_in[5];
  const float* W2  = (const float*)d_in[6];
  const float* b2  = (const float*)d_in[7];
  const float* W3  = (const float*)d_in[8];
  const float* b3  = (const float*)d_in[9];
  const float* W4  = (const float*)d_in[10];
  const float* b4  = (const float*)d_in[11];
  const float* cw  = (const float*)d_in[12];

  const int S = 8, KS = 512;    // 157x8 = 1256 blocks; KS multiple of 64 -> even steps

  float* base = (float*)d_ws;
  float* part = base;                         // 8M floats (dead after k_epi; CSR aliases)
  float* x1   = base + 8000000;               // 1M
  float* zA   = base + 9000000;               // 120000
  float* zB   = base + 9120000;               // 120000
  unsigned short* Bph = (unsigned short*)(base + 9240000);   // 237568 ushorts
  unsigned short* Bpl = (unsigned short*)(base + 9360000);   // 237568 ushorts
  // total ~9.48M floats = 38 MB (ws proven >= 58 MB by round-2/4 S=13 branch)

  // CSR arrays alias the part region (part dead by then)
  int*  cnt  = (int*)base;                    // 20001
  int*  off  = (int*)base + 24576;            // 20001
  int*  cur  = (int*)base + 49152;            // 20001
  int2* ent  = (int2*)((int*)base + 73728);   // 1.28M int2 -> ends at 2,633,728 ints
  float* partial = base + 2700000;            // 8 x 120000 -> ends 3,660,000

  k_packB<<<(NKB * 4 * 64 * 8 + 255) / 256, 256, 0, stream>>>(W1, Bph, Bpl);
  k_gemm1<<<dim3(157, S), 256, 0, stream>>>(A, Bph, Bpl, part, KS);
  k_epi<<<(M_NODES * NH + 255) / 256, 256, 0, stream>>>(part, b1, x1, S);
  k_mlp<<<(M_NODES + 31) / 32, 256, 0, stream>>>(x1, W2, b2, W3, b3, W4, b4, zA);

  hipMemsetAsync(cnt, 0, (M_NODES + 1) * sizeof(int), stream);
  k_count<<<(N_EDGES_C + 255) / 256, 256, 0, stream>>>(sx, sy, cnt);
  k_scan<<<1, 1024, 0, stream>>>(cnt, off, cur);
  k_scatter<<<(N_EDGES_C + 255) / 256, 256, 0, stream>>>(sx, sy, rel, cur, ent);

  float* zc = zA;
  float* zn = zB;
  for (int l = 0; l < 3; ++l) {
    k_gather<<<(M_NODES * 8 + 255) / 256, 256, 0, stream>>>(zc, off, ent, cw + 6 * l, partial);
    k_combine<<<(M_NODES * NC + 255) / 256, 256, 0, stream>>>(zc, partial, zn);
    float* t = zc; zc = zn; zn = t;
  }
  k_softmax<<<(M_NODES + 255) / 256, 256, 0, stream>>>(zc, (float*)d_out);
}